// Round 4
// baseline (176.530 us; speedup 1.0000x reference)
//
#include <hip/hip_runtime.h>
#include <cstdint>

#define OUT_S_OFF 33554432ull   // 8*4096*64*16

typedef short s16x8 __attribute__((ext_vector_type(8)));
typedef float f32x4 __attribute__((ext_vector_type(4)));
typedef unsigned int u32x2 __attribute__((ext_vector_type(2)));

// ---------------- compile-time geometric algebra tables ----------------
constexpr int BM_[16]   = {0,1,2,4,8,3,5,9,6,10,12,7,11,13,14,15};
constexpr int IDXm_[16] = {0,1,2,5,3,6,8,11,4,7,9,12,10,13,14,15};
constexpr int G_[16]    = {0,1,1,1,1,2,2,2,2,2,2,3,3,3,3,4};
constexpr int SRC_[16]  = {0,0,2,3,4,2,3,4,8,9,10,8,9,10,14,14};
constexpr int HASP_[16] = {0,1,0,0,0,1,1,1,0,0,0,1,1,1,0,1};
constexpr int A2_[16]   = {0,5,0,0,0,6,6,6,0,0,0,7,7,7,0,8};

constexpr int pcnt_(int x){ int c=0; for(int b=0;b<8;b++) c += (x>>b)&1; return c; }
constexpr int par_(int A,int B){ int sw=0; for(int b=0;b<4;b++) if((B>>b)&1) sw += pcnt_(A>>(b+1)); return (sw&1)?-1:1; }
constexpr int sgnv_(int b){ return par_(BM_[b], 15 & ~BM_[b]); }

struct GTab { int cnt[16]; signed char jj[16][16]; signed char kk[16][16]; signed char ss[16][16]; };

constexpr GTab mk_cayley(){
  GTab t{};
  for(int j=0;j<16;j++) for(int k=0;k<16;k++){
    int A=BM_[j], B=BM_[k];
    if(A & B & 1) continue;
    int i = IDXm_[A^B]; int s = par_(A,B);
    int n = t.cnt[i]; t.jj[i][n]=(signed char)j; t.kk[i][n]=(signed char)k; t.ss[i][n]=(signed char)s; t.cnt[i]=n+1;
  }
  return t;
}
constexpr GTab mk_join(){
  GTab t{};
  for(int j=0;j<16;j++) for(int k=0;k<16;k++){
    int cj = 15 & ~BM_[j], ck = 15 & ~BM_[k];
    if(cj & ck) continue;
    int m  = cj | ck;
    int w  = par_(cj, ck);
    int mp = IDXm_[15 & ~m];
    int s  = sgnv_(j)*sgnv_(k)*w*sgnv_(mp);
    int n = t.cnt[mp]; t.jj[mp][n]=(signed char)j; t.kk[mp][n]=(signed char)k; t.ss[mp][n]=(signed char)s; t.cnt[mp]=n+1;
  }
  return t;
}

__device__ __forceinline__ unsigned short f2bf(float f){
  unsigned u = __float_as_uint(f);
  return (unsigned short)((u + 0x7fffu + ((u>>16)&1u)) >> 16);
}
__device__ __forceinline__ unsigned int pack2(float a, float b){
  return (unsigned int)f2bf(a) | ((unsigned int)f2bf(b) << 16);
}

// ---------------- prepacked weight fragments (B-operand order) ----------------
__device__ unsigned short g_WinB [4*16*4*2*512];  // [m][i][s(4)][h(2)][512]
__device__ unsigned short g_WoutB[16*6*4*512];    // [i][s(6)][nt(4)][512]
__device__ unsigned short g_WsB  [6*4*512];       // [s(6)][nt(4)][512]

__global__ __launch_bounds__(256) void prepack(
    const float* wL, const float* wR, const float* wJL, const float* wJR, const float* wO,
    const float* s2L, const float* s2R, const float* s2JL, const float* s2JR,
    const float* s2O, const float* mv2s, const float* s2s)
{
  int idx = blockIdx.x*256 + threadIdx.x;
  if (idx < 262144) {                       // g_WinB
    int j = idx&7, l=(idx>>3)&63, h=(idx>>9)&1, s=(idx>>10)&3, i=(idx>>12)&15, m=idx>>16;
    int y = h*16 + (l&15), k = ((l>>4)&3)*8 + j;
    const float* w  = (m==0)?wL:(m==1)?wR:(m==2)?wJL:wJR;
    const float* s2 = (m==0)?s2L:(m==1)?s2R:(m==2)?s2JL:s2JR;
    float v = 0.f;
    if (s < 2)            v = w[(y*64 + s*32 + k)*9 + G_[i]];
    else if (HASP_[i])    v = w[(y*64 + (s-2)*32 + k)*9 + A2_[i]];
    else if (i == 0)      v = s2[y*64 + (s-2)*32 + k];
    g_WinB[idx] = f2bf(v);
  } else if (idx < 458752) {                // g_WoutB
    int t2 = idx - 262144;
    int j = t2&7, l=(t2>>3)&63, nt=(t2>>9)&3, rest=t2>>11;
    int s = rest % 6, i = rest / 6;
    int y = nt*16 + (l&15), k = ((l>>4)&3)*8 + j;
    float v = 0.f;
    if (s < 2)                    v = wO[(y*64 + s*32 + k)*9 + G_[i]];
    else if (s < 4 && HASP_[i])   v = wO[(y*64 + (s-2)*32 + k)*9 + A2_[i]];
    else if (i == 0)              v = s2O[y*128 + (s-2)*32 + k];
    g_WoutB[t2] = f2bf(v);
  } else if (idx < 471040) {                // g_WsB
    int t3 = idx - 458752;
    int j = t3&7, l=(t3>>3)&63, nt=(t3>>9)&3, s=t3>>11;
    int ys = nt*16 + (l&15), k = ((l>>4)&3)*8 + j;
    float v = (s < 2) ? mv2s[ys*64 + s*32 + k] : s2s[ys*128 + (s-2)*32 + k];
    g_WsB[t3] = f2bf(v);
  }
}

// ---------------- fused main kernel ----------------
// 256 threads = 4 waves, 16 tokens/block.
// wave roles P1/P2: (g = wv>>1 : 0=gp(L,R), 1=join(JL,JR)) x (h = wv&1 : y-half)
// wave roles P3: nt = wv (16-col tile of the 64 output channels)
__global__ __launch_bounds__(256, 4) void fused(
    const float* __restrict__ mv1, const float* __restrict__ mv2,
    const float* __restrict__ sc1, const float* __restrict__ sc2,
    const float* __restrict__ refmv, const float* __restrict__ bias,
    float* __restrict__ out)
{
  __shared__ unsigned int s_mv[8192];   // [(i*16+t)*32 + dw], 32KB; aliased as hidden later
  __shared__ unsigned int s_sc[1024];   // [t*64 + dw], 4KB  (s_cat bf16, swizzled)
  __shared__ float s_ref[16];

  const int tid  = threadIdx.x;
  const int lane = tid & 63, wv = tid >> 6;
  const int tr   = lane & 15, u = lane >> 4;
  const int g    = wv >> 1,  h = wv & 1;
  const size_t tok0 = (size_t)blockIdx.x * 16;

  // ---- staging helpers (load half-tile to regs; write half-tile to LDS) ----
  auto stage_load = [&](const float* __restrict__ src, int it, float4* Fr){
    int flat = tid + it*256;
    int x2 = flat & 31, t = flat >> 5;
    const float* b0 = src + (tok0+t)*1024 + x2*32;
    #pragma unroll
    for (int q=0;q<4;q++){
      Fr[q]   = *(const float4*)(b0 + q*4);
      Fr[4+q] = *(const float4*)(b0 + 16 + q*4);
    }
  };
  auto stage_write = [&](int it, const float4* Fr){
    int flat = tid + it*256;
    int x2 = flat & 31, t = flat >> 5;
    unsigned int* dst = &s_mv[t*32 + (x2 ^ ((t&7)<<2))];
    #pragma unroll
    for (int q=0;q<4;q++){
      #pragma unroll
      for (int e=0;e<4;e++){
        int i = q*4 + e;
        dst[i*512] = pack2(((const float*)&Fr[q])[e], ((const float*)&Fr[4+q])[e]);
      }
    }
  };

  // ---- A-fragment readers (swizzle-consistent with staging) ----
  auto afrag = [&](int comp, int sh)->s16x8 {
    const unsigned short* p = (const unsigned short*)s_mv;
    return *(const s16x8*)&p[(comp*16 + tr)*64 + (((sh*4 + u) ^ (tr&7)) << 3)];
  };
  auto scfrag = [&](int ss)->s16x8 {
    const unsigned short* p = (const unsigned short*)s_sc;
    return *(const s16x8*)&p[tr*128 + (((ss*4 + u) ^ (tr&7)) << 3)];
  };
  auto bfragIn = [&](int m,int i,int s)->s16x8 {
    return *(const s16x8*)&g_WinB[((((m*16+i)*4+s)*2+h)*512) + lane*8];
  };
  auto bfragOut = [&](int i,int s,int nt)->s16x8 {
    return *(const s16x8*)&g_WoutB[(((i*6+s)*4+nt)*512) + lane*8];
  };
  auto bfragS = [&](int s,int nt)->s16x8 {
    return *(const s16x8*)&g_WsB[((s*4+nt)*512) + lane*8];
  };

  // ---- P0: stage scalars, ref, mv1 ----
  {
    float4 F0[8], F1[8];
    stage_load(mv1, 0, F0);
    stage_load(mv1, 1, F1);
    #pragma unroll
    for (int it=0; it<4; ++it){
      int flat = tid + it*256;
      int cp = flat & 63, t = flat >> 6;
      float a, b;
      if (cp < 32){ const float* p = sc1 + (tok0+t)*64 + cp*2;      a=p[0]; b=p[1]; }
      else        { const float* p = sc2 + (tok0+t)*64 + (cp-32)*2; a=p[0]; b=p[1]; }
      s_sc[t*64 + (cp ^ ((t&7)<<2))] = pack2(a,b);
    }
    if (tid < 16) s_ref[tid] = refmv[(tok0+tid)*16 + 15];
    stage_write(0, F0);
    stage_write(1, F1);
  }
  __syncthreads();

  // ---- prefetch first half of mv2 into registers (hidden under P1a) ----
  float4 PF[8];
  stage_load(mv2, 0, PF);

  // ---- P1a: maps from mv1 (gp: L ; join: JL); sc1 folded; pack acc to bf16 ----
  u32x2 accAp[16], accBp[16];
  {
    const int m = (g==0) ? 0 : 2;
    #pragma unroll
    for (int i=0;i<16;i++){
      f32x4 a = (f32x4)0.f;
      a = __builtin_amdgcn_mfma_f32_16x16x32_bf16(afrag(i,0), bfragIn(m,i,0), a,0,0,0);
      a = __builtin_amdgcn_mfma_f32_16x16x32_bf16(afrag(i,1), bfragIn(m,i,1), a,0,0,0);
      if (HASP_[i]){
        a = __builtin_amdgcn_mfma_f32_16x16x32_bf16(afrag(SRC_[i],0), bfragIn(m,i,2), a,0,0,0);
        a = __builtin_amdgcn_mfma_f32_16x16x32_bf16(afrag(SRC_[i],1), bfragIn(m,i,3), a,0,0,0);
      } else if (i==0){
        a = __builtin_amdgcn_mfma_f32_16x16x32_bf16(scfrag(0), bfragIn(m,0,2), a,0,0,0);
        a = __builtin_amdgcn_mfma_f32_16x16x32_bf16(scfrag(1), bfragIn(m,0,3), a,0,0,0);
      }
      accAp[i].x = pack2(a[0], a[1]);
      accAp[i].y = pack2(a[2], a[3]);
    }
  }
  __syncthreads();

  // ---- P1b: write prefetched mv2 half; load+write second half ----
  stage_write(0, PF);
  {
    float4 F1[8];
    stage_load(mv2, 1, F1);
    stage_write(1, F1);
  }
  __syncthreads();

  // ---- P1c: maps from mv2 (gp: R ; join: JR); sc2 folded; pack acc ----
  {
    const int m = (g==0) ? 1 : 3;
    #pragma unroll
    for (int i=0;i<16;i++){
      f32x4 a = (f32x4)0.f;
      a = __builtin_amdgcn_mfma_f32_16x16x32_bf16(afrag(i,0), bfragIn(m,i,0), a,0,0,0);
      a = __builtin_amdgcn_mfma_f32_16x16x32_bf16(afrag(i,1), bfragIn(m,i,1), a,0,0,0);
      if (HASP_[i]){
        a = __builtin_amdgcn_mfma_f32_16x16x32_bf16(afrag(SRC_[i],0), bfragIn(m,i,2), a,0,0,0);
        a = __builtin_amdgcn_mfma_f32_16x16x32_bf16(afrag(SRC_[i],1), bfragIn(m,i,3), a,0,0,0);
      } else if (i==0){
        a = __builtin_amdgcn_mfma_f32_16x16x32_bf16(scfrag(2), bfragIn(m,0,2), a,0,0,0);
        a = __builtin_amdgcn_mfma_f32_16x16x32_bf16(scfrag(3), bfragIn(m,0,3), a,0,0,0);
      }
      accBp[i].x = pack2(a[0], a[1]);
      accBp[i].y = pack2(a[2], a[3]);
    }
  }
  __syncthreads();

  // ---- P2: Cayley GP / join from packed-bf16 regs; write hidden (aliases s_mv) ----
  {
    unsigned short* hidp = (unsigned short*)s_mv;
    if (g == 0){
      constexpr GTab CAY = mk_cayley();
      #pragma unroll
      for (int r=0;r<4;r++){
        const int t = u*4 + r;
        float L[16], R[16];
        #pragma unroll
        for (int j2=0;j2<16;j2++){
          unsigned wa = (r&2) ? accAp[j2].y : accAp[j2].x;
          unsigned wb = (r&2) ? accBp[j2].y : accBp[j2].x;
          L[j2] = __uint_as_float((r&1) ? (wa & 0xffff0000u) : (wa << 16));
          R[j2] = __uint_as_float((r&1) ? (wb & 0xffff0000u) : (wb << 16));
        }
        const int c = h*16 + tr;
        #pragma unroll
        for (int i=0;i<16;i++){
          float a = 0.f;
          #pragma unroll
          for (int e=0;e<CAY.cnt[i];e++){
            float p = L[(int)CAY.jj[i][e]] * R[(int)CAY.kk[i][e]];
            a = (CAY.ss[i][e] > 0) ? (a + p) : (a - p);
          }
          hidp[(i*16 + t)*64 + (c ^ ((t&7)<<3))] = f2bf(a);
        }
      }
    } else {
      constexpr GTab JNT = mk_join();
      #pragma unroll
      for (int r=0;r<4;r++){
        const int t = u*4 + r;
        float rv = s_ref[t];
        float L[16], R[16];
        #pragma unroll
        for (int j2=0;j2<16;j2++){
          unsigned wa = (r&2) ? accAp[j2].y : accAp[j2].x;
          unsigned wb = (r&2) ? accBp[j2].y : accBp[j2].x;
          L[j2] = __uint_as_float((r&1) ? (wa & 0xffff0000u) : (wa << 16));
          R[j2] = __uint_as_float((r&1) ? (wb & 0xffff0000u) : (wb << 16));
        }
        const int c = 32 + h*16 + tr;
        #pragma unroll
        for (int i=0;i<16;i++){
          float a = 0.f;
          #pragma unroll
          for (int e=0;e<JNT.cnt[i];e++){
            float p = L[(int)JNT.jj[i][e]] * R[(int)JNT.kk[i][e]];
            a = (JNT.ss[i][e] > 0) ? (a + p) : (a - p);
          }
          hidp[(i*16 + t)*64 + (c ^ ((t&7)<<3))] = f2bf(a * rv);
        }
      }
    }
  }
  __syncthreads();

  // ---- P3: output equi-linear + scalar head via MFMA; wave = n-tile ----
  {
    const int nt = wv;
    f32x4 accO[16]; f32x4 accS = (f32x4)0.f;
    #pragma unroll
    for (int i=0;i<16;i++) accO[i] = (f32x4)0.f;

    s16x8 h00 = afrag(0,0), h01 = afrag(0,1);   // hidden comp 0 (shared with out_s)

    #pragma unroll
    for (int i=0;i<16;i++){
      s16x8 a0 = (i==0) ? h00 : afrag(i,0);
      s16x8 a1 = (i==0) ? h01 : afrag(i,1);
      accO[i] = __builtin_amdgcn_mfma_f32_16x16x32_bf16(a0, bfragOut(i,0,nt), accO[i],0,0,0);
      accO[i] = __builtin_amdgcn_mfma_f32_16x16x32_bf16(a1, bfragOut(i,1,nt), accO[i],0,0,0);
      if (HASP_[i]){
        accO[i] = __builtin_amdgcn_mfma_f32_16x16x32_bf16(afrag(SRC_[i],0), bfragOut(i,2,nt), accO[i],0,0,0);
        accO[i] = __builtin_amdgcn_mfma_f32_16x16x32_bf16(afrag(SRC_[i],1), bfragOut(i,3,nt), accO[i],0,0,0);
      } else if (i==0){
        #pragma unroll
        for (int ss=0;ss<4;ss++)
          accO[0] = __builtin_amdgcn_mfma_f32_16x16x32_bf16(scfrag(ss), bfragOut(0,2+ss,nt), accO[0],0,0,0);
      }
    }
    // scalar head: bias + mv2s·hidden[:,0] + s2s·s_cat
    accS = __builtin_amdgcn_mfma_f32_16x16x32_bf16(h00, bfragS(0,nt), accS,0,0,0);
    accS = __builtin_amdgcn_mfma_f32_16x16x32_bf16(h01, bfragS(1,nt), accS,0,0,0);
    #pragma unroll
    for (int ss=0;ss<4;ss++)
      accS = __builtin_amdgcn_mfma_f32_16x16x32_bf16(scfrag(ss), bfragS(2+ss,nt), accS,0,0,0);

    const int y = nt*16 + tr;
    const float bv = bias[y];
    #pragma unroll
    for (int r=0;r<4;r++){
      const int t = u*4 + r;
      out[OUT_S_OFF + (tok0+t)*64 + y] = accS[r] + bv;
      float* ob = out + (tok0+t)*1024 + y*16;
      #pragma unroll
      for (int iq=0;iq<4;iq++){
        f32x4 v = { accO[iq*4+0][r], accO[iq*4+1][r], accO[iq*4+2][r], accO[iq*4+3][r] };
        *(f32x4*)(ob + iq*4) = v;
      }
    }
  }
}

extern "C" void kernel_launch(void* const* d_in, const int* in_sizes, int n_in,
                              void* d_out, int out_size, void* d_ws, size_t ws_size,
                              hipStream_t stream) {
  const float* mv1   = (const float*)d_in[0];
  const float* mv2   = (const float*)d_in[1];
  const float* sc1   = (const float*)d_in[2];
  const float* sc2   = (const float*)d_in[3];
  const float* refmv = (const float*)d_in[4];
  const float* wL    = (const float*)d_in[5];
  const float* s2L   = (const float*)d_in[6];
  const float* wR    = (const float*)d_in[7];
  const float* s2R   = (const float*)d_in[8];
  const float* wJL   = (const float*)d_in[9];
  const float* s2JL  = (const float*)d_in[10];
  const float* wJR   = (const float*)d_in[11];
  const float* s2JR  = (const float*)d_in[12];
  const float* wO    = (const float*)d_in[13];
  const float* s2O   = (const float*)d_in[14];
  const float* mv2s  = (const float*)d_in[15];
  const float* s2s   = (const float*)d_in[16];
  const float* bias  = (const float*)d_in[17];
  float* out = (float*)d_out;

  prepack<<<1840, 256, 0, stream>>>(wL,wR,wJL,wJR,wO, s2L,s2R,s2JL,s2JR, s2O, mv2s, s2s);
  fused<<<2048, 256, 0, stream>>>(mv1, mv2, sc1, sc2, refmv, bias, out);
}

// Round 5
// 151.542 us; speedup vs baseline: 1.1649x; 1.1649x over previous
//
#include <hip/hip_runtime.h>
#include <cstdint>

#define OUT_S_OFF 33554432ull   // 8*4096*64*16

typedef short s16x8 __attribute__((ext_vector_type(8)));
typedef float f32x4 __attribute__((ext_vector_type(4)));
typedef unsigned int u32x2 __attribute__((ext_vector_type(2)));

// ---------------- compile-time geometric algebra tables ----------------
constexpr int BM_[16]   = {0,1,2,4,8,3,5,9,6,10,12,7,11,13,14,15};
constexpr int IDXm_[16] = {0,1,2,5,3,6,8,11,4,7,9,12,10,13,14,15};
constexpr int G_[16]    = {0,1,1,1,1,2,2,2,2,2,2,3,3,3,3,4};
constexpr int SRC_[16]  = {0,0,2,3,4,2,3,4,8,9,10,8,9,10,14,14};
constexpr int HASP_[16] = {0,1,0,0,0,1,1,1,0,0,0,1,1,1,0,1};
constexpr int A2_[16]   = {0,5,0,0,0,6,6,6,0,0,0,7,7,7,0,8};

constexpr int pcnt_(int x){ int c=0; for(int b=0;b<8;b++) c += (x>>b)&1; return c; }
constexpr int par_(int A,int B){ int sw=0; for(int b=0;b<4;b++) if((B>>b)&1) sw += pcnt_(A>>(b+1)); return (sw&1)?-1:1; }
constexpr int sgnv_(int b){ return par_(BM_[b], 15 & ~BM_[b]); }

struct GTab { int cnt[16]; signed char jj[16][16]; signed char kk[16][16]; signed char ss[16][16]; };

constexpr GTab mk_cayley(){
  GTab t{};
  for(int j=0;j<16;j++) for(int k=0;k<16;k++){
    int A=BM_[j], B=BM_[k];
    if(A & B & 1) continue;
    int i = IDXm_[A^B]; int s = par_(A,B);
    int n = t.cnt[i]; t.jj[i][n]=(signed char)j; t.kk[i][n]=(signed char)k; t.ss[i][n]=(signed char)s; t.cnt[i]=n+1;
  }
  return t;
}
constexpr GTab mk_join(){
  GTab t{};
  for(int j=0;j<16;j++) for(int k=0;k<16;k++){
    int cj = 15 & ~BM_[j], ck = 15 & ~BM_[k];
    if(cj & ck) continue;
    int m  = cj | ck;
    int w  = par_(cj, ck);
    int mp = IDXm_[15 & ~m];
    int s  = sgnv_(j)*sgnv_(k)*w*sgnv_(mp);
    int n = t.cnt[mp]; t.jj[mp][n]=(signed char)j; t.kk[mp][n]=(signed char)k; t.ss[mp][n]=(signed char)s; t.cnt[mp]=n+1;
  }
  return t;
}

__device__ __forceinline__ unsigned short f2bf(float f){
  unsigned u = __float_as_uint(f);
  return (unsigned short)((u + 0x7fffu + ((u>>16)&1u)) >> 16);
}
__device__ __forceinline__ unsigned int pack2(float a, float b){
  return (unsigned int)f2bf(a) | ((unsigned int)f2bf(b) << 16);
}

// ---------------- prepacked weight fragments (B-operand order) ----------------
__device__ unsigned short g_WinB [4*16*4*2*512];  // [m][i][s(4)][h(2)][512]
__device__ unsigned short g_WoutB[16*6*4*512];    // [i][s(6)][nt(4)][512]
__device__ unsigned short g_WsB  [6*4*512];       // [s(6)][nt(4)][512]

__global__ __launch_bounds__(256) void prepack(
    const float* wL, const float* wR, const float* wJL, const float* wJR, const float* wO,
    const float* s2L, const float* s2R, const float* s2JL, const float* s2JR,
    const float* s2O, const float* mv2s, const float* s2s)
{
  int idx = blockIdx.x*256 + threadIdx.x;
  if (idx < 262144) {                       // g_WinB
    int j = idx&7, l=(idx>>3)&63, h=(idx>>9)&1, s=(idx>>10)&3, i=(idx>>12)&15, m=idx>>16;
    int y = h*16 + (l&15), k = ((l>>4)&3)*8 + j;
    const float* w  = (m==0)?wL:(m==1)?wR:(m==2)?wJL:wJR;
    const float* s2 = (m==0)?s2L:(m==1)?s2R:(m==2)?s2JL:s2JR;
    float v = 0.f;
    if (s < 2)            v = w[(y*64 + s*32 + k)*9 + G_[i]];
    else if (HASP_[i])    v = w[(y*64 + (s-2)*32 + k)*9 + A2_[i]];
    else if (i == 0)      v = s2[y*64 + (s-2)*32 + k];
    g_WinB[idx] = f2bf(v);
  } else if (idx < 458752) {                // g_WoutB
    int t2 = idx - 262144;
    int j = t2&7, l=(t2>>3)&63, nt=(t2>>9)&3, rest=t2>>11;
    int s = rest % 6, i = rest / 6;
    int y = nt*16 + (l&15), k = ((l>>4)&3)*8 + j;
    float v = 0.f;
    if (s < 2)                    v = wO[(y*64 + s*32 + k)*9 + G_[i]];
    else if (s < 4 && HASP_[i])   v = wO[(y*64 + (s-2)*32 + k)*9 + A2_[i]];
    else if (i == 0)              v = s2O[y*128 + (s-2)*32 + k];
    g_WoutB[t2] = f2bf(v);
  } else if (idx < 471040) {                // g_WsB
    int t3 = idx - 458752;
    int j = t3&7, l=(t3>>3)&63, nt=(t3>>9)&3, s=t3>>11;
    int ys = nt*16 + (l&15), k = ((l>>4)&3)*8 + j;
    float v = (s < 2) ? mv2s[ys*64 + s*32 + k] : s2s[ys*128 + (s-2)*32 + k];
    g_WsB[t3] = f2bf(v);
  }
}

// ---------------- fused main kernel ----------------
// 256 threads = 4 waves, 16 tokens/block; dual mv LDS buffers (both input
// streams issued at block start — single exposed HBM round trip).
// wave roles P1/P2: (g = wv>>1 : 0=gp(L,R), 1=join(JL,JR)) x (h = wv&1 : y-half)
// wave roles P3: nt = wv (16-col tile of the 64 output channels)
__global__ __launch_bounds__(256, 2) void fused(
    const float* __restrict__ mv1, const float* __restrict__ mv2,
    const float* __restrict__ sc1, const float* __restrict__ sc2,
    const float* __restrict__ refmv, const float* __restrict__ bias,
    float* __restrict__ out)
{
  __shared__ unsigned int s_mvA[8192];  // mv1 tile; later hidden
  __shared__ unsigned int s_mvB[8192];  // mv2 tile
  __shared__ unsigned int s_sc[1024];   // s_cat bf16, swizzled
  __shared__ float s_ref[16];

  const int tid  = threadIdx.x;
  const int lane = tid & 63, wv = tid >> 6;
  const int tr   = lane & 15, u = lane >> 4;
  const int g    = wv >> 1,  h = wv & 1;
  const size_t tok0 = (size_t)blockIdx.x * 16;

  auto stage_load = [&](const float* __restrict__ src, int it, float4* Fr){
    int flat = tid + it*256;
    int x2 = flat & 31, t = flat >> 5;
    const float* b0 = src + (tok0+t)*1024 + x2*32;
    #pragma unroll
    for (int q=0;q<4;q++){
      Fr[q]   = *(const float4*)(b0 + q*4);
      Fr[4+q] = *(const float4*)(b0 + 16 + q*4);
    }
  };
  auto stage_write = [&](unsigned int* sbuf, int it, const float4* Fr){
    int flat = tid + it*256;
    int x2 = flat & 31, t = flat >> 5;
    unsigned int* dst = &sbuf[t*32 + (x2 ^ ((t&7)<<2))];
    #pragma unroll
    for (int q=0;q<4;q++){
      #pragma unroll
      for (int e=0;e<4;e++){
        int i = q*4 + e;
        dst[i*512] = pack2(((const float*)&Fr[q])[e], ((const float*)&Fr[4+q])[e]);
      }
    }
  };

  auto afrag = [&](const unsigned int* sbuf, int comp, int sh)->s16x8 {
    const unsigned short* p = (const unsigned short*)sbuf;
    return *(const s16x8*)&p[(comp*16 + tr)*64 + (((sh*4 + u) ^ (tr&7)) << 3)];
  };
  auto scfrag = [&](int ss)->s16x8 {
    const unsigned short* p = (const unsigned short*)s_sc;
    return *(const s16x8*)&p[tr*128 + (((ss*4 + u) ^ (tr&7)) << 3)];
  };
  auto bfragIn = [&](int m,int i,int s)->s16x8 {
    return *(const s16x8*)&g_WinB[((((m*16+i)*4+s)*2+h)*512) + lane*8];
  };
  auto bfragOut = [&](int i,int s,int nt)->s16x8 {
    return *(const s16x8*)&g_WoutB[(((i*6+s)*4+nt)*512) + lane*8];
  };
  auto bfragS = [&](int s,int nt)->s16x8 {
    return *(const s16x8*)&g_WsB[((s*4+nt)*512) + lane*8];
  };

  // ---- P0: issue BOTH mv streams up front; interleave pack/write ----
  {
    float4 F0[8], F1[8];
    stage_load(mv1, 0, F0);
    stage_load(mv1, 1, F1);
    #pragma unroll
    for (int it=0; it<4; ++it){
      int flat = tid + it*256;
      int cp = flat & 63, t = flat >> 6;
      float a, b;
      if (cp < 32){ const float* p = sc1 + (tok0+t)*64 + cp*2;      a=p[0]; b=p[1]; }
      else        { const float* p = sc2 + (tok0+t)*64 + (cp-32)*2; a=p[0]; b=p[1]; }
      s_sc[t*64 + (cp ^ ((t&7)<<2))] = pack2(a,b);
    }
    if (tid < 16) s_ref[tid] = refmv[(tok0+tid)*16 + 15];
    stage_write(s_mvA, 0, F0);
    float4 G0[8];
    stage_load(mv2, 0, G0);
    stage_write(s_mvA, 1, F1);
    float4 G1[8];
    stage_load(mv2, 1, G1);
    stage_write(s_mvB, 0, G0);
    stage_write(s_mvB, 1, G1);
  }
  __syncthreads();

  // ---- P1: all four input linears in one phase (two independent MFMA chains) ----
  u32x2 accAp[16], accBp[16];
  {
    const int mA = (g==0) ? 0 : 2;
    const int mB = (g==0) ? 1 : 3;
    #pragma unroll
    for (int i=0;i<16;i++){
      f32x4 a = (f32x4)0.f, b = (f32x4)0.f;
      a = __builtin_amdgcn_mfma_f32_16x16x32_bf16(afrag(s_mvA,i,0), bfragIn(mA,i,0), a,0,0,0);
      b = __builtin_amdgcn_mfma_f32_16x16x32_bf16(afrag(s_mvB,i,0), bfragIn(mB,i,0), b,0,0,0);
      a = __builtin_amdgcn_mfma_f32_16x16x32_bf16(afrag(s_mvA,i,1), bfragIn(mA,i,1), a,0,0,0);
      b = __builtin_amdgcn_mfma_f32_16x16x32_bf16(afrag(s_mvB,i,1), bfragIn(mB,i,1), b,0,0,0);
      if (HASP_[i]){
        a = __builtin_amdgcn_mfma_f32_16x16x32_bf16(afrag(s_mvA,SRC_[i],0), bfragIn(mA,i,2), a,0,0,0);
        b = __builtin_amdgcn_mfma_f32_16x16x32_bf16(afrag(s_mvB,SRC_[i],0), bfragIn(mB,i,2), b,0,0,0);
        a = __builtin_amdgcn_mfma_f32_16x16x32_bf16(afrag(s_mvA,SRC_[i],1), bfragIn(mA,i,3), a,0,0,0);
        b = __builtin_amdgcn_mfma_f32_16x16x32_bf16(afrag(s_mvB,SRC_[i],1), bfragIn(mB,i,3), b,0,0,0);
      } else if (i==0){
        a = __builtin_amdgcn_mfma_f32_16x16x32_bf16(scfrag(0), bfragIn(mA,0,2), a,0,0,0);
        b = __builtin_amdgcn_mfma_f32_16x16x32_bf16(scfrag(2), bfragIn(mB,0,2), b,0,0,0);
        a = __builtin_amdgcn_mfma_f32_16x16x32_bf16(scfrag(1), bfragIn(mA,0,3), a,0,0,0);
        b = __builtin_amdgcn_mfma_f32_16x16x32_bf16(scfrag(3), bfragIn(mB,0,3), b,0,0,0);
      }
      accAp[i].x = pack2(a[0], a[1]);
      accAp[i].y = pack2(a[2], a[3]);
      accBp[i].x = pack2(b[0], b[1]);
      accBp[i].y = pack2(b[2], b[3]);
    }
  }
  __syncthreads();   // all reads of s_mvA done before hidden overwrite

  // ---- P2: Cayley GP / join from packed-bf16 regs; write hidden (aliases s_mvA) ----
  {
    unsigned short* hidp = (unsigned short*)s_mvA;
    if (g == 0){
      constexpr GTab CAY = mk_cayley();
      #pragma unroll
      for (int r=0;r<4;r++){
        const int t = u*4 + r;
        float L[16], R[16];
        #pragma unroll
        for (int j2=0;j2<16;j2++){
          unsigned wa = (r&2) ? accAp[j2].y : accAp[j2].x;
          unsigned wb = (r&2) ? accBp[j2].y : accBp[j2].x;
          L[j2] = __uint_as_float((r&1) ? (wa & 0xffff0000u) : (wa << 16));
          R[j2] = __uint_as_float((r&1) ? (wb & 0xffff0000u) : (wb << 16));
        }
        const int c = h*16 + tr;
        #pragma unroll
        for (int i=0;i<16;i++){
          float a = 0.f;
          #pragma unroll
          for (int e=0;e<CAY.cnt[i];e++){
            float p = L[(int)CAY.jj[i][e]] * R[(int)CAY.kk[i][e]];
            a = (CAY.ss[i][e] > 0) ? (a + p) : (a - p);
          }
          hidp[(i*16 + t)*64 + (c ^ ((t&7)<<3))] = f2bf(a);
        }
      }
    } else {
      constexpr GTab JNT = mk_join();
      #pragma unroll
      for (int r=0;r<4;r++){
        const int t = u*4 + r;
        float rv = s_ref[t];
        float L[16], R[16];
        #pragma unroll
        for (int j2=0;j2<16;j2++){
          unsigned wa = (r&2) ? accAp[j2].y : accAp[j2].x;
          unsigned wb = (r&2) ? accBp[j2].y : accBp[j2].x;
          L[j2] = __uint_as_float((r&1) ? (wa & 0xffff0000u) : (wa << 16));
          R[j2] = __uint_as_float((r&1) ? (wb & 0xffff0000u) : (wb << 16));
        }
        const int c = 32 + h*16 + tr;
        #pragma unroll
        for (int i=0;i<16;i++){
          float a = 0.f;
          #pragma unroll
          for (int e=0;e<JNT.cnt[i];e++){
            float p = L[(int)JNT.jj[i][e]] * R[(int)JNT.kk[i][e]];
            a = (JNT.ss[i][e] > 0) ? (a + p) : (a - p);
          }
          hidp[(i*16 + t)*64 + (c ^ ((t&7)<<3))] = f2bf(a * rv);
        }
      }
    }
  }
  __syncthreads();

  // ---- P3: output equi-linear + scalar head via MFMA; wave = n-tile ----
  {
    const int nt = wv;
    f32x4 accO[16]; f32x4 accS = (f32x4)0.f;
    #pragma unroll
    for (int i=0;i<16;i++) accO[i] = (f32x4)0.f;

    s16x8 h00 = afrag(s_mvA,0,0), h01 = afrag(s_mvA,0,1);

    #pragma unroll
    for (int i=0;i<16;i++){
      s16x8 a0 = (i==0) ? h00 : afrag(s_mvA,i,0);
      s16x8 a1 = (i==0) ? h01 : afrag(s_mvA,i,1);
      accO[i] = __builtin_amdgcn_mfma_f32_16x16x32_bf16(a0, bfragOut(i,0,nt), accO[i],0,0,0);
      accO[i] = __builtin_amdgcn_mfma_f32_16x16x32_bf16(a1, bfragOut(i,1,nt), accO[i],0,0,0);
      if (HASP_[i]){
        accO[i] = __builtin_amdgcn_mfma_f32_16x16x32_bf16(afrag(s_mvA,SRC_[i],0), bfragOut(i,2,nt), accO[i],0,0,0);
        accO[i] = __builtin_amdgcn_mfma_f32_16x16x32_bf16(afrag(s_mvA,SRC_[i],1), bfragOut(i,3,nt), accO[i],0,0,0);
      } else if (i==0){
        #pragma unroll
        for (int ss=0;ss<4;ss++)
          accO[0] = __builtin_amdgcn_mfma_f32_16x16x32_bf16(scfrag(ss), bfragOut(0,2+ss,nt), accO[0],0,0,0);
      }
    }
    accS = __builtin_amdgcn_mfma_f32_16x16x32_bf16(h00, bfragS(0,nt), accS,0,0,0);
    accS = __builtin_amdgcn_mfma_f32_16x16x32_bf16(h01, bfragS(1,nt), accS,0,0,0);
    #pragma unroll
    for (int ss=0;ss<4;ss++)
      accS = __builtin_amdgcn_mfma_f32_16x16x32_bf16(scfrag(ss), bfragS(2+ss,nt), accS,0,0,0);

    const int y = nt*16 + tr;
    const float bv = bias[y];
    #pragma unroll
    for (int r=0;r<4;r++){
      const int t = u*4 + r;
      out[OUT_S_OFF + (tok0+t)*64 + y] = accS[r] + bv;
      float* ob = out + (tok0+t)*1024 + y*16;
      #pragma unroll
      for (int iq=0;iq<4;iq++){
        f32x4 v = { accO[iq*4+0][r], accO[iq*4+1][r], accO[iq*4+2][r], accO[iq*4+3][r] };
        *(f32x4*)(ob + iq*4) = v;
      }
    }
  }
}

extern "C" void kernel_launch(void* const* d_in, const int* in_sizes, int n_in,
                              void* d_out, int out_size, void* d_ws, size_t ws_size,
                              hipStream_t stream) {
  const float* mv1   = (const float*)d_in[0];
  const float* mv2   = (const float*)d_in[1];
  const float* sc1   = (const float*)d_in[2];
  const float* sc2   = (const float*)d_in[3];
  const float* refmv = (const float*)d_in[4];
  const float* wL    = (const float*)d_in[5];
  const float* s2L   = (const float*)d_in[6];
  const float* wR    = (const float*)d_in[7];
  const float* s2R   = (const float*)d_in[8];
  const float* wJL   = (const float*)d_in[9];
  const float* s2JL  = (const float*)d_in[10];
  const float* wJR   = (const float*)d_in[11];
  const float* s2JR  = (const float*)d_in[12];
  const float* wO    = (const float*)d_in[13];
  const float* s2O   = (const float*)d_in[14];
  const float* mv2s  = (const float*)d_in[15];
  const float* s2s   = (const float*)d_in[16];
  const float* bias  = (const float*)d_in[17];
  float* out = (float*)d_out;

  prepack<<<1840, 256, 0, stream>>>(wL,wR,wJL,wJR,wO, s2L,s2R,s2JL,s2JR, s2O, mv2s, s2s);
  fused<<<2048, 256, 0, stream>>>(mv1, mv2, sc1, sc2, refmv, bias, out);
}